// Round 12
// baseline (44.904 us; speedup 1.0000x reference)
//
#include <hip/hip_runtime.h>
#include <math.h>

#define G     1000
#define B     32
#define NC    2048
#define NT    2048
#define BN    (B * NT)
#define LOG2E 1.4426950408889634f
#define LN2PI 1.8378770664093453f   // ln(2*pi)

#if __has_builtin(__builtin_amdgcn_exp2f)
#define EXP2F(x) __builtin_amdgcn_exp2f(x)
#else
#define EXP2F(x) exp2f(x)
#endif

// d_ws float layout: h[0,64000) | yg[64000,128000) | packed weights:
#define PW1F4 128000   // 32 f4
#define PW1S  128128   // 32 f
#define PW2F4 128160   // 512 f4
#define PW2S  130208   // 512 f
#define PW3F4 130720   // 512 f4
#define PW3S  132768   // 512 f
#define PW4F4 133280   // 32 f4
#define PW4S  133408   // 32 f

// ---------------------------------------------------------------------------
// Kernel A v5 (frozen) + embedded weight-prep in block (0,0).
// All smooth blocks finish before k_conv starts (stream order) -> race-free.
// ---------------------------------------------------------------------------
__global__ __launch_bounds__(512) void k_smooth(
    const float* __restrict__ xc, const float* __restrict__ yc,
    const float* __restrict__ ls_x, float* __restrict__ h,
    float* __restrict__ loss_slot,
    const float* __restrict__ W1, const float* __restrict__ W2,
    const float* __restrict__ W3, const float* __restrict__ W4,
    float* __restrict__ ws) {
  __shared__ float2 sxy[NC];              // {s*x_n, y_n}, 16KB
  __shared__ float2 part[8][128];         // per-wave {h0,h1} partials, 8KB

  int tid = threadIdx.x;
  int b = blockIdx.y, tile = blockIdx.x;

  if (tile == 0 && b == 0) {              // weight prep (trivial)
    if (tid == 0) *loss_slot = 0.f;
    float4* p1 = (float4*)(ws + PW1F4); float4* p2 = (float4*)(ws + PW2F4);
    float4* p3 = (float4*)(ws + PW3F4); float4* p4 = (float4*)(ws + PW4F4);
    if (tid < 32)  { int oc = tid >> 1, ic = tid & 1,  a = oc * 10 + ic * 5;
      p1[oc * 2 + ic]  = make_float4(W1[a], W1[a+1], W1[a+2], W1[a+3]);
      ws[PW1S + ic * 16 + oc] = W1[a + 4]; }
    for (int i = tid; i < 512; i += 512) { int oc = i >> 4, ic = i & 15, a = oc * 80 + ic * 5;
      p2[oc * 16 + ic] = make_float4(W2[a], W2[a+1], W2[a+2], W2[a+3]);
      ws[PW2S + ic * 32 + oc] = W2[a + 4]; }
    for (int i = tid; i < 512; i += 512) { int oc = i >> 5, ic = i & 31, a = oc * 160 + ic * 5;
      p3[oc * 32 + ic] = make_float4(W3[a], W3[a+1], W3[a+2], W3[a+3]);
      ws[PW3S + ic * 16 + oc] = W3[a + 4]; }
    if (tid < 32)  { int oc = tid >> 4, ic = tid & 15, a = oc * 80 + ic * 5;
      p4[oc * 16 + ic] = make_float4(W4[a], W4[a+1], W4[a+2], W4[a+3]);
      ws[PW4S + ic * 2 + oc] = W4[a + 4]; }
  }

  float ls  = ls_x[0];
  float s   = sqrtf(0.5f * LOG2E) / ls;   // w = exp2(-(s*t - s*x)^2)
  float dlt = s * (4.4f / 999.f);

  const float* xb = xc + b * NC;
  const float* yb = yc + b * NC;
  for (int n = tid; n < NC; n += 512) sxy[n] = make_float2(s * xb[n], yb[n]);
  __syncthreads();

  int lane = tid & 63, w = tid >> 6;      // w = n-slice (256 n)
  int ns = lane & 7, gr = lane >> 3;      // 8 n-subs x 8 g-runs
  int g0 = tile * 128 + gr * 16;
  float v0 = s * -2.2f + dlt * (float)g0;
  float r  = EXP2F(-2.f * dlt * dlt);

  float h0[16], h1[16];
  #pragma unroll
  for (int j = 0; j < 16; ++j) { h0[j] = 0.f; h1[j] = 0.f; }

  const float2* base = sxy + w * 256 + ns;
  #pragma unroll 4
  for (int i = 0; i < 32; ++i) {
    float2 v = base[i * 8];
    float a = v.x - v0;
    float W = EXP2F(64.f - a * a);
    float q = EXP2F(fmaf(2.f * dlt, a, -dlt * dlt));
    #pragma unroll
    for (int j = 0; j < 16; ++j) {
      h0[j] += W;
      h1[j] = fmaf(W, v.y, h1[j]);
      W *= q; q *= r;
    }
  }
  #pragma unroll
  for (int m = 1; m < 8; m <<= 1) {
    #pragma unroll
    for (int j = 0; j < 16; ++j) {
      h0[j] += __shfl_xor(h0[j], m);
      h1[j] += __shfl_xor(h1[j], m);
    }
  }
  {
    int j0 = ns * 2;
    part[w][gr * 16 + j0]     = make_float2(h0[j0], h1[j0]);
    part[w][gr * 16 + j0 + 1] = make_float2(h0[j0 + 1], h1[j0 + 1]);
  }
  __syncthreads();

  if (tid < 128) {
    int g = tile * 128 + tid;
    if (g < G) {
      float d0 = 0.f, d1 = 0.f;
      #pragma unroll
      for (int k = 0; k < 8; ++k) { float2 pv = part[k][tid]; d0 += pv.x; d1 += pv.y; }
      d0 *= 0x1p-64f;
      d1 *= 0x1p-64f;
      h[(b * 2 + 0) * G + g] = d0;
      h[(b * 2 + 1) * G + g] = d1 / (d0 + 1e-8f);
    }
  }
}

// ---------------------------------------------------------------------------
// Kernel B v7: TILE=32, grid (32 x B) = 1024 blocks = exactly 4/CU (16 waves
// /CU, 2x all prior convs). NO weight LDS: weights read from pre-transposed
// global (L2-resident, loop-invariant per ic -> compiler clusters loads).
// LDS = 2 x 32ch x CSTR=52 = 13.3KB. Stage g in [ts-10, ts+42).
// Chain: L1 writes [2,50) -> L2 clean [4,48) -> L3 clean [6,46) -> L4 reads
// [8,44) ✓ (clean cells never read unwritten LDS; fmaxf kills stray NaN).
// ---------------------------------------------------------------------------
#define TILE  32
#define NTILE 32   // 32*32 = 1024 >= 1000
#define CSTR  52

template <int CIN, int COUT, int NSUB>
__device__ __forceinline__ void conv8g(
    const float* __restrict__ in, float* __restrict__ out,
    const float4* __restrict__ wf4, const float* __restrict__ w4p,
    const float* __restrict__ bias, int tid) {
  if (tid < COUT * NSUB) {
    int oc = tid % COUT;
    int i0 = (tid / COUT) * 8;            // reads [i0,i0+12), writes [i0+2,i0+10)
    float acc[8];
    float bb = bias[oc];
    #pragma unroll
    for (int p = 0; p < 8; ++p) acc[p] = bb;
    #pragma unroll
    for (int ic = 0; ic < CIN; ++ic) {
      const float4* ip = (const float4*)(in + ic * CSTR + i0);
      float4 A = ip[0], Bv = ip[1], C = ip[2];
      float v[12] = {A.x, A.y, A.z, A.w, Bv.x, Bv.y, Bv.z, Bv.w, C.x, C.y, C.z, C.w};
      float4 w = wf4[oc * CIN + ic];
      float w4v = w4p[ic * COUT + oc];
      #pragma unroll
      for (int p = 0; p < 8; ++p)
        acc[p] = fmaf(v[p], w.x, fmaf(v[p+1], w.y, fmaf(v[p+2], w.z,
                 fmaf(v[p+3], w.w, fmaf(v[p+4], w4v, acc[p])))));
    }
    float* op = out + oc * CSTR + i0 + 2;
    #pragma unroll
    for (int j = 0; j < 4; ++j)
      *(float2*)(op + 2 * j) = make_float2(fmaxf(acc[2*j], 0.f), fmaxf(acc[2*j+1], 0.f));
  }
}

__global__ __launch_bounds__(256, 4) void k_conv(
    const float* __restrict__ h,
    const float* __restrict__ Bs1, const float* __restrict__ Bs2,
    const float* __restrict__ Bs3, const float* __restrict__ Bs4,
    const float* __restrict__ ws, float* __restrict__ yg) {
  __shared__ __align__(16) float bufA[32 * CSTR], bufB[32 * CSTR];

  int tid  = threadIdx.x;
  int tile = blockIdx.x, b = blockIdx.y;
  int ts   = tile * TILE;

  const float4* pw1 = (const float4*)(ws + PW1F4);
  const float4* pw2 = (const float4*)(ws + PW2F4);
  const float4* pw3 = (const float4*)(ws + PW3F4);
  const float4* pw4 = (const float4*)(ws + PW4F4);

  // stage input: col i in [0,52) <-> global g = ts + i - 10
  for (int i = tid; i < 2 * CSTR; i += 256) {
    int c = i >= CSTR, col = i - c * CSTR;
    int g = ts + col - 10;
    bufA[c * CSTR + col] = (g >= 0 && g < G) ? h[(b * 2 + c) * G + g] : 0.f;
  }
  __syncthreads();

  conv8g<2, 16, 6>(bufA, bufB, pw1, ws + PW1S, Bs1, tid);   // 96 thr
  __syncthreads();
  conv8g<16, 32, 6>(bufB, bufA, pw2, ws + PW2S, Bs2, tid);  // 192 thr
  __syncthreads();
  conv8g<32, 16, 6>(bufA, bufB, pw3, ws + PW3S, Bs3, tid);  // 96 thr
  __syncthreads();

  // Layer 4: 64 threads, thread -> (oc, one output); softplus on ch1
  if (tid < 64) {
    int oc = tid >= 32;
    int j  = tid - oc * 32;               // 0..31
    int i  = 10 + j;                      // reads cols [8,44)
    int gp = ts + j;
    if (gp < G) {
      float sacc = Bs4[oc];
      #pragma unroll
      for (int ic = 0; ic < 16; ++ic) {
        const float* ip = bufB + ic * CSTR + i - 2;
        float4 w = pw4[oc * 16 + ic];
        float w4v = ws[PW4S + ic * 2 + oc];
        sacc = fmaf(ip[0], w.x, fmaf(ip[1], w.y, fmaf(ip[2], w.z,
               fmaf(ip[3], w.w, fmaf(ip[4], w4v, sacc)))));
      }
      if (oc == 0) {
        yg[(b * 2 + 0) * G + gp] = sacc;
      } else {
        float sp_ = fmaxf(sacc, 0.f) + log1pf(__expf(-fabsf(sacc)));
        yg[(b * 2 + 1) * G + gp] = sp_;
      }
    }
  }
}

// ---------------------------------------------------------------------------
// Kernel C v6 (frozen): Gaussian recurrence, 2 t/thread, f4 g-pair staging.
// ---------------------------------------------------------------------------
__global__ __launch_bounds__(512) void k_pred(
    const float* __restrict__ xt, const float* __restrict__ yt,
    const float* __restrict__ ls_rho, const float* __restrict__ yg,
    float* __restrict__ out) {
  __shared__ float4 sp[512];
  __shared__ float pA0[512], pA1[512], pB0[512], pB1[512];
  __shared__ float red[8];

  int tid = threadIdx.x;
  int b = blockIdx.y, tile = blockIdx.x;
  float ls = ls_rho[0];
  float s  = sqrtf(0.5f * LOG2E) / ls;
  float dl = s * (4.4f / 999.f);

  const float* y0 = yg + (b * 2 + 0) * G;
  const float* y1 = yg + (b * 2 + 1) * G;
  {
    int g0 = 2 * tid, g1 = 2 * tid + 1;
    float a0 = (g0 < G) ? y0[g0] : 0.f, b0_ = (g0 < G) ? y1[g0] : 0.f;
    float a1 = (g1 < G) ? y0[g1] : 0.f, b1_ = (g1 < G) ? y1[g1] : 0.f;
    sp[tid] = make_float4(a0, b0_, a1, b1_);
  }
  __syncthreads();

  int lane = tid & 63, wv = tid >> 6;
  int ta = tile * 128 + lane;
  float ua = s * xt[b * NT + ta];
  float ub = s * xt[b * NT + ta + 64];
  float base = 2.2f * s - dl * (float)(wv * 128);
  float aa = ua + base, ab = ub + base;
  float Wa = EXP2F(64.f - aa * aa), qa = EXP2F(dl * (aa + aa) - dl * dl);
  float Wb = EXP2F(64.f - ab * ab), qb = EXP2F(dl * (ab + ab) - dl * dl);
  float r  = EXP2F(-2.f * dl * dl);

  float muA = 0.f, sgA = 0.f, muB = 0.f, sgB = 0.f;
  const float4* p = sp + wv * 64;
  #pragma unroll 4
  for (int i = 0; i < 64; ++i) {
    float4 v = p[i];
    muA = fmaf(Wa, v.x, muA); sgA = fmaf(Wa, v.y, sgA); Wa *= qa; qa *= r;
    muB = fmaf(Wb, v.x, muB); sgB = fmaf(Wb, v.y, sgB); Wb *= qb; qb *= r;
    muA = fmaf(Wa, v.z, muA); sgA = fmaf(Wa, v.w, sgA); Wa *= qa; qa *= r;
    muB = fmaf(Wb, v.z, muB); sgB = fmaf(Wb, v.w, sgB); Wb *= qb; qb *= r;
  }
  pA0[tid] = muA; pA1[tid] = sgA; pB0[tid] = muB; pB1[tid] = sgB;
  __syncthreads();

  float lp = 0.f;
  if (tid < 128) {
    int which = tid >> 6, l = tid & 63;
    int t = tile * 128 + which * 64 + l;
    const float* q0 = which ? pB0 : pA0;
    const float* q1 = which ? pB1 : pA1;
    float mu = 0.f, sg = 0.f;
    #pragma unroll
    for (int k = 0; k < 8; ++k) { mu += q0[l + 64 * k]; sg += q1[l + 64 * k]; }
    mu *= 0x1p-64f;
    sg *= 0x1p-64f;
    out[b * NT + t]      = mu;
    out[BN + b * NT + t] = sg;
    float z = (yt[b * NT + t] - mu) / sg;
    lp = -0.5f * z * z - __logf(sg) - 0.5f * LN2PI;
  }
  #pragma unroll
  for (int m = 32; m; m >>= 1) lp += __shfl_xor(lp, m);
  if ((tid & 63) == 0) red[tid >> 6] = lp;
  __syncthreads();
  if (tid == 0) {
    float tot = 0.f;
    #pragma unroll
    for (int i = 0; i < 8; ++i) tot += red[i];
    atomicAdd(out + 2 * BN, -tot * (1.f / (float)NT));
  }
}

extern "C" void kernel_launch(void* const* d_in, const int* in_sizes, int n_in,
                              void* d_out, int out_size, void* d_ws, size_t ws_size,
                              hipStream_t stream) {
  const float* xc  = (const float*)d_in[0];
  const float* yc  = (const float*)d_in[1];
  const float* xt  = (const float*)d_in[2];
  const float* yt  = (const float*)d_in[3];
  const float* lsx = (const float*)d_in[4];
  const float* lsr = (const float*)d_in[5];
  const float* W1  = (const float*)d_in[6];  const float* b1 = (const float*)d_in[7];
  const float* W2  = (const float*)d_in[8];  const float* b2 = (const float*)d_in[9];
  const float* W3  = (const float*)d_in[10]; const float* b3 = (const float*)d_in[11];
  const float* W4  = (const float*)d_in[12]; const float* b4 = (const float*)d_in[13];

  float* out = (float*)d_out;
  float* ws  = (float*)d_ws;
  float* h   = ws;                  // B*2*G
  float* yg  = ws + B * 2 * G;      // B*2*G

  k_smooth<<<dim3(8, B), 512, 0, stream>>>(xc, yc, lsx, h, out + 2 * BN,
                                           W1, W2, W3, W4, ws);
  k_conv<<<dim3(NTILE, B), 256, 0, stream>>>(h, b1, b2, b3, b4, ws, yg);
  k_pred<<<dim3(16, B), 512, 0, stream>>>(xt, yt, lsr, yg, out);
}

// Round 13
// 41.763 us; speedup vs baseline: 1.0752x; 1.0752x over previous
//
#include <hip/hip_runtime.h>
#include <math.h>

#define G     1000
#define B     32
#define NC    2048
#define NT    2048
#define BN    (B * NT)
#define LOG2E 1.4426950408889634f
#define LN2PI 1.8378770664093453f   // ln(2*pi)

#if __has_builtin(__builtin_amdgcn_exp2f)
#define EXP2F(x) __builtin_amdgcn_exp2f(x)
#else
#define EXP2F(x) exp2f(x)
#endif

// ---------------------------------------------------------------------------
// Kernel A v6: Gaussian recurrence along g, 64-g tiles. Grid (16, B) = 512
// blocks = 2/CU (16 waves/CU vs v5's 8) and 8-step serial chain (vs 16).
// Block 512 = 8 n-slice waves x (8 g-runs x 8 n-subs); lane owns 8 g + 32 n.
// W scaled 2^64 (a^2 <= ~130 -> no flush). LDS 20KB.
// ---------------------------------------------------------------------------
__global__ __launch_bounds__(512) void k_smooth(
    const float* __restrict__ xc, const float* __restrict__ yc,
    const float* __restrict__ ls_x, float* __restrict__ h,
    float* __restrict__ loss_slot) {
  __shared__ float2 sxy[NC];              // {s*x_n, y_n}, 16KB
  __shared__ float2 part[8][64];          // per-wave {h0,h1} partials, 4KB
  if (blockIdx.x == 0 && blockIdx.y == 0 && threadIdx.x == 0) *loss_slot = 0.f;

  int tid = threadIdx.x;
  int b = blockIdx.y, tile = blockIdx.x;  // tile covers g in [64*tile, 64*tile+64)
  float ls  = ls_x[0];
  float s   = sqrtf(0.5f * LOG2E) / ls;   // w = exp2(-(s*t - s*x)^2)
  float dlt = s * (4.4f / 999.f);

  const float* xb = xc + b * NC;
  const float* yb = yc + b * NC;
  for (int n = tid; n < NC; n += 512) sxy[n] = make_float2(s * xb[n], yb[n]);
  __syncthreads();

  int lane = tid & 63, w = tid >> 6;      // w = n-slice (256 n)
  int ns = lane & 7, gr = lane >> 3;      // 8 n-subs x 8 g-runs (8 g each)
  int g0 = tile * 64 + gr * 8;
  float v0 = s * -2.2f + dlt * (float)g0; // s*t at g0
  float r  = EXP2F(-2.f * dlt * dlt);

  float h0[8], h1[8];
  #pragma unroll
  for (int j = 0; j < 8; ++j) { h0[j] = 0.f; h1[j] = 0.f; }

  const float2* base = sxy + w * 256 + ns;  // lane's n: +8 per step
  #pragma unroll 4
  for (int i = 0; i < 32; ++i) {
    float2 v = base[i * 8];
    float a = v.x - v0;                   // u - v_g0
    float W = EXP2F(64.f - a * a);        // 2^64-scaled first weight
    float q = EXP2F(fmaf(2.f * dlt, a, -dlt * dlt));
    #pragma unroll
    for (int j = 0; j < 8; ++j) {
      h0[j] += W;
      h1[j] = fmaf(W, v.y, h1[j]);
      W *= q; q *= r;
    }
  }
  // reduce over the 8 n-subs (lane bits 0..2)
  #pragma unroll
  for (int m = 1; m < 8; m <<= 1) {
    #pragma unroll
    for (int j = 0; j < 8; ++j) {
      h0[j] += __shfl_xor(h0[j], m);
      h1[j] += __shfl_xor(h1[j], m);
    }
  }
  // after reduce, all 8 ns-lanes of a run hold the same h0/h1; lane ns stores g-slot ns
  part[w][gr * 8 + ns] = make_float2(h0[ns], h1[ns]);
  __syncthreads();

  if (tid < 64) {
    int g = tile * 64 + tid;
    if (g < G) {
      float d0 = 0.f, d1 = 0.f;
      #pragma unroll
      for (int k = 0; k < 8; ++k) { float2 pv = part[k][tid]; d0 += pv.x; d1 += pv.y; }
      d0 *= 0x1p-64f;                     // undo 2^64 scaling
      d1 *= 0x1p-64f;
      h[(b * 2 + 0) * G + g] = d0;
      h[(b * 2 + 1) * G + g] = d1 / (d0 + 1e-8f);
    }
  }
}

// ---------------------------------------------------------------------------
// Kernel B v6 (reverted to r11 best): POS=8, packed f4 weights in LDS.
// TILE=48, grid (21 x B).
// ---------------------------------------------------------------------------
#define TILE  48
#define NTILE 21   // 21*48 = 1008 >= 1000
#define CSTR  68

template <int CIN, int COUT, int S4>
__device__ __forceinline__ void conv8(
    const float* __restrict__ in, float* __restrict__ out,
    const float4* __restrict__ wf4, const float* __restrict__ w4p,
    const float* __restrict__ bias, int tid) {
  if (tid < COUT * 8) {
    int oc = tid % COUT;
    int i0 = (tid / COUT) * 8;            // reads [i0,i0+12), writes [i0+2,i0+10)
    float acc[8];
    float bb = bias[oc];
    #pragma unroll
    for (int p = 0; p < 8; ++p) acc[p] = bb;
    for (int ic = 0; ic < CIN; ++ic) {
      const float4* ip = (const float4*)(in + ic * CSTR + i0);
      float4 A = ip[0], Bv = ip[1], C = ip[2];
      float v[12] = {A.x, A.y, A.z, A.w, Bv.x, Bv.y, Bv.z, Bv.w, C.x, C.y, C.z, C.w};
      float4 w = wf4[oc * S4 + ic];
      float w4v = w4p[ic * COUT + oc];
      #pragma unroll
      for (int p = 0; p < 8; ++p)
        acc[p] = fmaf(v[p], w.x, fmaf(v[p+1], w.y, fmaf(v[p+2], w.z,
                 fmaf(v[p+3], w.w, fmaf(v[p+4], w4v, acc[p])))));
    }
    float* op = out + oc * CSTR + i0 + 2;
    #pragma unroll
    for (int j = 0; j < 4; ++j)
      *(float2*)(op + 2 * j) = make_float2(fmaxf(acc[2*j], 0.f), fmaxf(acc[2*j+1], 0.f));
  }
}

__global__ __launch_bounds__(256, 2) void k_conv(
    const float* __restrict__ h,
    const float* __restrict__ W1, const float* __restrict__ Bs1,
    const float* __restrict__ W2, const float* __restrict__ Bs2,
    const float* __restrict__ W3, const float* __restrict__ Bs3,
    const float* __restrict__ W4, const float* __restrict__ Bs4,
    float* __restrict__ yg) {
  __shared__ __align__(16) float bufA[32 * CSTR], bufB[32 * CSTR];
  __shared__ float4 wf1[16 * 3], wf2[32 * 17], wf3[16 * 33];
  __shared__ float  w41[2 * 16], w42[16 * 32], w43[32 * 16];
  __shared__ float  wt4[162];
  __shared__ float  sB1[16], sB2[32], sB3[16], sB4[2];

  int tid  = threadIdx.x;
  int tile = blockIdx.x, b = blockIdx.y;
  int ts   = tile * TILE;

  if (tid < 32) {                         // L1: oc<16, ic<2
    int oc = tid >> 1, ic = tid & 1, a = oc * 10 + ic * 5;
    wf1[oc * 3 + ic] = make_float4(W1[a], W1[a+1], W1[a+2], W1[a+3]);
    w41[ic * 16 + oc] = W1[a + 4];
  }
  for (int pr = tid; pr < 512; pr += 256) {   // L2: oc<32, ic<16
    int oc = pr >> 4, ic = pr & 15, a = oc * 80 + ic * 5;
    wf2[oc * 17 + ic] = make_float4(W2[a], W2[a+1], W2[a+2], W2[a+3]);
    w42[ic * 32 + oc] = W2[a + 4];
  }
  for (int pr = tid; pr < 512; pr += 256) {   // L3: oc<16, ic<32
    int oc = pr >> 5, ic = pr & 31, a = oc * 160 + ic * 5;
    wf3[oc * 33 + ic] = make_float4(W3[a], W3[a+1], W3[a+2], W3[a+3]);
    w43[ic * 16 + oc] = W3[a + 4];
  }
  for (int i = tid; i < 160; i += 256) wt4[(i / 80) * 81 + i % 80] = W4[i];
  if (tid < 16)       sB1[tid]      = Bs1[tid];
  else if (tid < 48)  sB2[tid - 16] = Bs2[tid - 16];
  else if (tid < 64)  sB3[tid - 48] = Bs3[tid - 48];
  else if (tid < 66)  sB4[tid - 64] = Bs4[tid - 64];

  for (int i = tid; i < 2 * CSTR; i += 256) {
    int c = i >= CSTR, col = i - c * CSTR;
    int g = ts + col - 10;
    bufA[c * CSTR + col] = (g >= 0 && g < G) ? h[(b * 2 + c) * G + g] : 0.f;
  }
  __syncthreads();

  conv8<2, 16, 3>(bufA, bufB, wf1, w41, sB1, tid);
  __syncthreads();
  conv8<16, 32, 17>(bufB, bufA, wf2, w42, sB2, tid);
  __syncthreads();
  conv8<32, 16, 33>(bufA, bufB, wf3, w43, sB3, tid);
  __syncthreads();

  if (tid < 96) {
    int oc = tid >= 48;
    int j  = tid - oc * 48;
    int i  = 10 + j;
    float sacc = sB4[oc];
    #pragma unroll
    for (int ic = 0; ic < 16; ++ic) {
      const float* ip = bufB + ic * CSTR + i - 2;
      #pragma unroll
      for (int k = 0; k < 5; ++k)
        sacc = fmaf(ip[k], wt4[oc * 81 + ic * 5 + k], sacc);
    }
    int gp = ts + j;
    if (gp < G) {
      if (oc == 0) {
        yg[(b * 2 + 0) * G + gp] = sacc;
      } else {
        float sp_ = fmaxf(sacc, 0.f) + log1pf(__expf(-fabsf(sacc)));
        yg[(b * 2 + 1) * G + gp] = sp_;
      }
    }
  }
}

// ---------------------------------------------------------------------------
// Kernel C v6 (frozen): Gaussian recurrence, 2 t/thread, f4 g-pair staging.
// ---------------------------------------------------------------------------
__global__ __launch_bounds__(512) void k_pred(
    const float* __restrict__ xt, const float* __restrict__ yt,
    const float* __restrict__ ls_rho, const float* __restrict__ yg,
    float* __restrict__ out) {
  __shared__ float4 sp[512];
  __shared__ float pA0[512], pA1[512], pB0[512], pB1[512];
  __shared__ float red[8];

  int tid = threadIdx.x;
  int b = blockIdx.y, tile = blockIdx.x;
  float ls = ls_rho[0];
  float s  = sqrtf(0.5f * LOG2E) / ls;
  float dl = s * (4.4f / 999.f);

  const float* y0 = yg + (b * 2 + 0) * G;
  const float* y1 = yg + (b * 2 + 1) * G;
  {
    int g0 = 2 * tid, g1 = 2 * tid + 1;
    float a0 = (g0 < G) ? y0[g0] : 0.f, b0_ = (g0 < G) ? y1[g0] : 0.f;
    float a1 = (g1 < G) ? y0[g1] : 0.f, b1_ = (g1 < G) ? y1[g1] : 0.f;
    sp[tid] = make_float4(a0, b0_, a1, b1_);
  }
  __syncthreads();

  int lane = tid & 63, wv = tid >> 6;
  int ta = tile * 128 + lane;
  float ua = s * xt[b * NT + ta];
  float ub = s * xt[b * NT + ta + 64];
  float base = 2.2f * s - dl * (float)(wv * 128);
  float aa = ua + base, ab = ub + base;
  float Wa = EXP2F(64.f - aa * aa), qa = EXP2F(dl * (aa + aa) - dl * dl);
  float Wb = EXP2F(64.f - ab * ab), qb = EXP2F(dl * (ab + ab) - dl * dl);
  float r  = EXP2F(-2.f * dl * dl);

  float muA = 0.f, sgA = 0.f, muB = 0.f, sgB = 0.f;
  const float4* p = sp + wv * 64;
  #pragma unroll 4
  for (int i = 0; i < 64; ++i) {
    float4 v = p[i];
    muA = fmaf(Wa, v.x, muA); sgA = fmaf(Wa, v.y, sgA); Wa *= qa; qa *= r;
    muB = fmaf(Wb, v.x, muB); sgB = fmaf(Wb, v.y, sgB); Wb *= qb; qb *= r;
    muA = fmaf(Wa, v.z, muA); sgA = fmaf(Wa, v.w, sgA); Wa *= qa; qa *= r;
    muB = fmaf(Wb, v.z, muB); sgB = fmaf(Wb, v.w, sgB); Wb *= qb; qb *= r;
  }
  pA0[tid] = muA; pA1[tid] = sgA; pB0[tid] = muB; pB1[tid] = sgB;
  __syncthreads();

  float lp = 0.f;
  if (tid < 128) {
    int which = tid >> 6, l = tid & 63;
    int t = tile * 128 + which * 64 + l;
    const float* q0 = which ? pB0 : pA0;
    const float* q1 = which ? pB1 : pA1;
    float mu = 0.f, sg = 0.f;
    #pragma unroll
    for (int k = 0; k < 8; ++k) { mu += q0[l + 64 * k]; sg += q1[l + 64 * k]; }
    mu *= 0x1p-64f;
    sg *= 0x1p-64f;
    out[b * NT + t]      = mu;
    out[BN + b * NT + t] = sg;
    float z = (yt[b * NT + t] - mu) / sg;
    lp = -0.5f * z * z - __logf(sg) - 0.5f * LN2PI;
  }
  #pragma unroll
  for (int m = 32; m; m >>= 1) lp += __shfl_xor(lp, m);
  if ((tid & 63) == 0) red[tid >> 6] = lp;
  __syncthreads();
  if (tid == 0) {
    float tot = 0.f;
    #pragma unroll
    for (int i = 0; i < 8; ++i) tot += red[i];
    atomicAdd(out + 2 * BN, -tot * (1.f / (float)NT));
  }
}

extern "C" void kernel_launch(void* const* d_in, const int* in_sizes, int n_in,
                              void* d_out, int out_size, void* d_ws, size_t ws_size,
                              hipStream_t stream) {
  const float* xc  = (const float*)d_in[0];
  const float* yc  = (const float*)d_in[1];
  const float* xt  = (const float*)d_in[2];
  const float* yt  = (const float*)d_in[3];
  const float* lsx = (const float*)d_in[4];
  const float* lsr = (const float*)d_in[5];
  const float* W1  = (const float*)d_in[6];  const float* b1 = (const float*)d_in[7];
  const float* W2  = (const float*)d_in[8];  const float* b2 = (const float*)d_in[9];
  const float* W3  = (const float*)d_in[10]; const float* b3 = (const float*)d_in[11];
  const float* W4  = (const float*)d_in[12]; const float* b4 = (const float*)d_in[13];

  float* out = (float*)d_out;
  float* h   = (float*)d_ws;        // B*2*G
  float* yg  = h + B * 2 * G;       // B*2*G

  k_smooth<<<dim3(16, B), 512, 0, stream>>>(xc, yc, lsx, h, out + 2 * BN);
  k_conv<<<dim3(NTILE, B), 256, 0, stream>>>(h, W1, b1, W2, b2, W3, b3, W4, b4, yg);
  k_pred<<<dim3(16, B), 512, 0, stream>>>(xt, yt, lsr, yg, out);
}

// Round 14
// 39.128 us; speedup vs baseline: 1.1476x; 1.0674x over previous
//
#include <hip/hip_runtime.h>
#include <math.h>

#define G     1000
#define B     32
#define NC    2048
#define NT    2048
#define BN    (B * NT)
#define LOG2E 1.4426950408889634f
#define LN2PI 1.8378770664093453f   // ln(2*pi)

#if __has_builtin(__builtin_amdgcn_exp2f)
#define EXP2F(x) __builtin_amdgcn_exp2f(x)
#else
#define EXP2F(x) exp2f(x)
#endif

// ---------------------------------------------------------------------------
// Kernel A v6 (frozen): Gaussian recurrence along g, 64-g tiles.
// Grid (16, B) = 512 blocks = 2/CU; 8-step serial chain.
// ---------------------------------------------------------------------------
__global__ __launch_bounds__(512) void k_smooth(
    const float* __restrict__ xc, const float* __restrict__ yc,
    const float* __restrict__ ls_x, float* __restrict__ h,
    float* __restrict__ loss_slot) {
  __shared__ float2 sxy[NC];              // {s*x_n, y_n}, 16KB
  __shared__ float2 part[8][64];          // per-wave {h0,h1} partials, 4KB
  if (blockIdx.x == 0 && blockIdx.y == 0 && threadIdx.x == 0) *loss_slot = 0.f;

  int tid = threadIdx.x;
  int b = blockIdx.y, tile = blockIdx.x;
  float ls  = ls_x[0];
  float s   = sqrtf(0.5f * LOG2E) / ls;   // w = exp2(-(s*t - s*x)^2)
  float dlt = s * (4.4f / 999.f);

  const float* xb = xc + b * NC;
  const float* yb = yc + b * NC;
  for (int n = tid; n < NC; n += 512) sxy[n] = make_float2(s * xb[n], yb[n]);
  __syncthreads();

  int lane = tid & 63, w = tid >> 6;      // w = n-slice (256 n)
  int ns = lane & 7, gr = lane >> 3;      // 8 n-subs x 8 g-runs (8 g each)
  int g0 = tile * 64 + gr * 8;
  float v0 = s * -2.2f + dlt * (float)g0;
  float r  = EXP2F(-2.f * dlt * dlt);

  float h0[8], h1[8];
  #pragma unroll
  for (int j = 0; j < 8; ++j) { h0[j] = 0.f; h1[j] = 0.f; }

  const float2* base = sxy + w * 256 + ns;
  #pragma unroll 4
  for (int i = 0; i < 32; ++i) {
    float2 v = base[i * 8];
    float a = v.x - v0;
    float W = EXP2F(64.f - a * a);
    float q = EXP2F(fmaf(2.f * dlt, a, -dlt * dlt));
    #pragma unroll
    for (int j = 0; j < 8; ++j) {
      h0[j] += W;
      h1[j] = fmaf(W, v.y, h1[j]);
      W *= q; q *= r;
    }
  }
  #pragma unroll
  for (int m = 1; m < 8; m <<= 1) {
    #pragma unroll
    for (int j = 0; j < 8; ++j) {
      h0[j] += __shfl_xor(h0[j], m);
      h1[j] += __shfl_xor(h1[j], m);
    }
  }
  part[w][gr * 8 + ns] = make_float2(h0[ns], h1[ns]);
  __syncthreads();

  if (tid < 64) {
    int g = tile * 64 + tid;
    if (g < G) {
      float d0 = 0.f, d1 = 0.f;
      #pragma unroll
      for (int k = 0; k < 8; ++k) { float2 pv = part[k][tid]; d0 += pv.x; d1 += pv.y; }
      d0 *= 0x1p-64f;
      d1 *= 0x1p-64f;
      h[(b * 2 + 0) * G + g] = d0;
      h[(b * 2 + 1) * G + g] = d1 / (d0 + 1e-8f);
    }
  }
}

// ---------------------------------------------------------------------------
// Kernel B v8: full-occupancy layer mapping. L1/L3 at POS=4 (16 subs x 16 oc
// = 256 threads, was 128), L2 POS=8 (256), L4 unchanged. L3 does the same
// FMA count as L2 (2560/pos) — halving its span is the payoff.
// TILE=48, CSTR=68, grid (21 x B). Valid chain unchanged:
// L1 writes [2,66) -> L2 clean [4,64) -> L3 clean [6,62) -> L4 reads [8,60).
// ---------------------------------------------------------------------------
#define TILE  48
#define NTILE 21   // 21*48 = 1008 >= 1000
#define CSTR  68

template <int CIN, int COUT, int S4>
__device__ __forceinline__ void conv8(
    const float* __restrict__ in, float* __restrict__ out,
    const float4* __restrict__ wf4, const float* __restrict__ w4p,
    const float* __restrict__ bias, int tid) {
  if (tid < COUT * 8) {
    int oc = tid % COUT;
    int i0 = (tid / COUT) * 8;            // reads [i0,i0+12), writes [i0+2,i0+10)
    float acc[8];
    float bb = bias[oc];
    #pragma unroll
    for (int p = 0; p < 8; ++p) acc[p] = bb;
    for (int ic = 0; ic < CIN; ++ic) {
      const float4* ip = (const float4*)(in + ic * CSTR + i0);
      float4 A = ip[0], Bv = ip[1], C = ip[2];
      float v[12] = {A.x, A.y, A.z, A.w, Bv.x, Bv.y, Bv.z, Bv.w, C.x, C.y, C.z, C.w};
      float4 w = wf4[oc * S4 + ic];
      float w4v = w4p[ic * COUT + oc];
      #pragma unroll
      for (int p = 0; p < 8; ++p)
        acc[p] = fmaf(v[p], w.x, fmaf(v[p+1], w.y, fmaf(v[p+2], w.z,
                 fmaf(v[p+3], w.w, fmaf(v[p+4], w4v, acc[p])))));
    }
    float* op = out + oc * CSTR + i0 + 2;
    #pragma unroll
    for (int j = 0; j < 4; ++j)
      *(float2*)(op + 2 * j) = make_float2(fmaxf(acc[2*j], 0.f), fmaxf(acc[2*j+1], 0.f));
  }
}

template <int CIN, int COUT, int S4>
__device__ __forceinline__ void conv4(
    const float* __restrict__ in, float* __restrict__ out,
    const float4* __restrict__ wf4, const float* __restrict__ w4p,
    const float* __restrict__ bias, int tid) {
  // 256 threads exactly: 16 subs x COUT(=16) oc. reads [i0,i0+8), writes [i0+2,i0+6)
  int oc = tid % COUT;
  int i0 = (tid / COUT) * 4;              // 0..60
  float acc[4];
  float bb = bias[oc];
  #pragma unroll
  for (int p = 0; p < 4; ++p) acc[p] = bb;
  for (int ic = 0; ic < CIN; ++ic) {
    const float4* ip = (const float4*)(in + ic * CSTR + i0);
    float4 A = ip[0], Bv = ip[1];
    float v[8] = {A.x, A.y, A.z, A.w, Bv.x, Bv.y, Bv.z, Bv.w};
    float4 w = wf4[oc * S4 + ic];
    float w4v = w4p[ic * COUT + oc];
    #pragma unroll
    for (int p = 0; p < 4; ++p)
      acc[p] = fmaf(v[p], w.x, fmaf(v[p+1], w.y, fmaf(v[p+2], w.z,
               fmaf(v[p+3], w.w, fmaf(v[p+4], w4v, acc[p])))));
  }
  float* op = out + oc * CSTR + i0 + 2;
  *(float2*)op       = make_float2(fmaxf(acc[0], 0.f), fmaxf(acc[1], 0.f));
  *(float2*)(op + 2) = make_float2(fmaxf(acc[2], 0.f), fmaxf(acc[3], 0.f));
}

__global__ __launch_bounds__(256, 2) void k_conv(
    const float* __restrict__ h,
    const float* __restrict__ W1, const float* __restrict__ Bs1,
    const float* __restrict__ W2, const float* __restrict__ Bs2,
    const float* __restrict__ W3, const float* __restrict__ Bs3,
    const float* __restrict__ W4, const float* __restrict__ Bs4,
    float* __restrict__ yg) {
  __shared__ __align__(16) float bufA[32 * CSTR], bufB[32 * CSTR];
  __shared__ float4 wf1[16 * 3], wf2[32 * 17], wf3[16 * 33];
  __shared__ float  w41[2 * 16], w42[16 * 32], w43[32 * 16];
  __shared__ float  wt4[162];
  __shared__ float  sB1[16], sB2[32], sB3[16], sB4[2];

  int tid  = threadIdx.x;
  int tile = blockIdx.x, b = blockIdx.y;
  int ts   = tile * TILE;

  if (tid < 32) {                         // L1: oc<16, ic<2
    int oc = tid >> 1, ic = tid & 1, a = oc * 10 + ic * 5;
    wf1[oc * 3 + ic] = make_float4(W1[a], W1[a+1], W1[a+2], W1[a+3]);
    w41[ic * 16 + oc] = W1[a + 4];
  }
  for (int pr = tid; pr < 512; pr += 256) {   // L2: oc<32, ic<16
    int oc = pr >> 4, ic = pr & 15, a = oc * 80 + ic * 5;
    wf2[oc * 17 + ic] = make_float4(W2[a], W2[a+1], W2[a+2], W2[a+3]);
    w42[ic * 32 + oc] = W2[a + 4];
  }
  for (int pr = tid; pr < 512; pr += 256) {   // L3: oc<16, ic<32
    int oc = pr >> 5, ic = pr & 31, a = oc * 160 + ic * 5;
    wf3[oc * 33 + ic] = make_float4(W3[a], W3[a+1], W3[a+2], W3[a+3]);
    w43[ic * 16 + oc] = W3[a + 4];
  }
  for (int i = tid; i < 160; i += 256) wt4[(i / 80) * 81 + i % 80] = W4[i];
  if (tid < 16)       sB1[tid]      = Bs1[tid];
  else if (tid < 48)  sB2[tid - 16] = Bs2[tid - 16];
  else if (tid < 64)  sB3[tid - 48] = Bs3[tid - 48];
  else if (tid < 66)  sB4[tid - 64] = Bs4[tid - 64];

  for (int i = tid; i < 2 * CSTR; i += 256) {
    int c = i >= CSTR, col = i - c * CSTR;
    int g = ts + col - 10;
    bufA[c * CSTR + col] = (g >= 0 && g < G) ? h[(b * 2 + c) * G + g] : 0.f;
  }
  __syncthreads();

  conv4<2, 16, 3>(bufA, bufB, wf1, w41, sB1, tid);     // 256 thr
  __syncthreads();
  conv8<16, 32, 17>(bufB, bufA, wf2, w42, sB2, tid);   // 256 thr
  __syncthreads();
  conv4<32, 16, 33>(bufA, bufB, wf3, w43, sB3, tid);   // 256 thr (was 128)
  __syncthreads();

  if (tid < 96) {
    int oc = tid >= 48;
    int j  = tid - oc * 48;
    int i  = 10 + j;
    float sacc = sB4[oc];
    #pragma unroll
    for (int ic = 0; ic < 16; ++ic) {
      const float* ip = bufB + ic * CSTR + i - 2;
      #pragma unroll
      for (int k = 0; k < 5; ++k)
        sacc = fmaf(ip[k], wt4[oc * 81 + ic * 5 + k], sacc);
    }
    int gp = ts + j;
    if (gp < G) {
      if (oc == 0) {
        yg[(b * 2 + 0) * G + gp] = sacc;
      } else {
        float sp_ = fmaxf(sacc, 0.f) + log1pf(__expf(-fabsf(sacc)));
        yg[(b * 2 + 1) * G + gp] = sp_;
      }
    }
  }
}

// ---------------------------------------------------------------------------
// Kernel C v6 (frozen): Gaussian recurrence, 2 t/thread, f4 g-pair staging.
// ---------------------------------------------------------------------------
__global__ __launch_bounds__(512) void k_pred(
    const float* __restrict__ xt, const float* __restrict__ yt,
    const float* __restrict__ ls_rho, const float* __restrict__ yg,
    float* __restrict__ out) {
  __shared__ float4 sp[512];
  __shared__ float pA0[512], pA1[512], pB0[512], pB1[512];
  __shared__ float red[8];

  int tid = threadIdx.x;
  int b = blockIdx.y, tile = blockIdx.x;
  float ls = ls_rho[0];
  float s  = sqrtf(0.5f * LOG2E) / ls;
  float dl = s * (4.4f / 999.f);

  const float* y0 = yg + (b * 2 + 0) * G;
  const float* y1 = yg + (b * 2 + 1) * G;
  {
    int g0 = 2 * tid, g1 = 2 * tid + 1;
    float a0 = (g0 < G) ? y0[g0] : 0.f, b0_ = (g0 < G) ? y1[g0] : 0.f;
    float a1 = (g1 < G) ? y0[g1] : 0.f, b1_ = (g1 < G) ? y1[g1] : 0.f;
    sp[tid] = make_float4(a0, b0_, a1, b1_);
  }
  __syncthreads();

  int lane = tid & 63, wv = tid >> 6;
  int ta = tile * 128 + lane;
  float ua = s * xt[b * NT + ta];
  float ub = s * xt[b * NT + ta + 64];
  float base = 2.2f * s - dl * (float)(wv * 128);
  float aa = ua + base, ab = ub + base;
  float Wa = EXP2F(64.f - aa * aa), qa = EXP2F(dl * (aa + aa) - dl * dl);
  float Wb = EXP2F(64.f - ab * ab), qb = EXP2F(dl * (ab + ab) - dl * dl);
  float r  = EXP2F(-2.f * dl * dl);

  float muA = 0.f, sgA = 0.f, muB = 0.f, sgB = 0.f;
  const float4* p = sp + wv * 64;
  #pragma unroll 4
  for (int i = 0; i < 64; ++i) {
    float4 v = p[i];
    muA = fmaf(Wa, v.x, muA); sgA = fmaf(Wa, v.y, sgA); Wa *= qa; qa *= r;
    muB = fmaf(Wb, v.x, muB); sgB = fmaf(Wb, v.y, sgB); Wb *= qb; qb *= r;
    muA = fmaf(Wa, v.z, muA); sgA = fmaf(Wa, v.w, sgA); Wa *= qa; qa *= r;
    muB = fmaf(Wb, v.z, muB); sgB = fmaf(Wb, v.w, sgB); Wb *= qb; qb *= r;
  }
  pA0[tid] = muA; pA1[tid] = sgA; pB0[tid] = muB; pB1[tid] = sgB;
  __syncthreads();

  float lp = 0.f;
  if (tid < 128) {
    int which = tid >> 6, l = tid & 63;
    int t = tile * 128 + which * 64 + l;
    const float* q0 = which ? pB0 : pA0;
    const float* q1 = which ? pB1 : pA1;
    float mu = 0.f, sg = 0.f;
    #pragma unroll
    for (int k = 0; k < 8; ++k) { mu += q0[l + 64 * k]; sg += q1[l + 64 * k]; }
    mu *= 0x1p-64f;
    sg *= 0x1p-64f;
    out[b * NT + t]      = mu;
    out[BN + b * NT + t] = sg;
    float z = (yt[b * NT + t] - mu) / sg;
    lp = -0.5f * z * z - __logf(sg) - 0.5f * LN2PI;
  }
  #pragma unroll
  for (int m = 32; m; m >>= 1) lp += __shfl_xor(lp, m);
  if ((tid & 63) == 0) red[tid >> 6] = lp;
  __syncthreads();
  if (tid == 0) {
    float tot = 0.f;
    #pragma unroll
    for (int i = 0; i < 8; ++i) tot += red[i];
    atomicAdd(out + 2 * BN, -tot * (1.f / (float)NT));
  }
}

extern "C" void kernel_launch(void* const* d_in, const int* in_sizes, int n_in,
                              void* d_out, int out_size, void* d_ws, size_t ws_size,
                              hipStream_t stream) {
  const float* xc  = (const float*)d_in[0];
  const float* yc  = (const float*)d_in[1];
  const float* xt  = (const float*)d_in[2];
  const float* yt  = (const float*)d_in[3];
  const float* lsx = (const float*)d_in[4];
  const float* lsr = (const float*)d_in[5];
  const float* W1  = (const float*)d_in[6];  const float* b1 = (const float*)d_in[7];
  const float* W2  = (const float*)d_in[8];  const float* b2 = (const float*)d_in[9];
  const float* W3  = (const float*)d_in[10]; const float* b3 = (const float*)d_in[11];
  const float* W4  = (const float*)d_in[12]; const float* b4 = (const float*)d_in[13];

  float* out = (float*)d_out;
  float* h   = (float*)d_ws;        // B*2*G
  float* yg  = h + B * 2 * G;       // B*2*G

  k_smooth<<<dim3(16, B), 512, 0, stream>>>(xc, yc, lsx, h, out + 2 * BN);
  k_conv<<<dim3(NTILE, B), 256, 0, stream>>>(h, W1, b1, W2, b2, W3, b3, W4, b4, yg);
  k_pred<<<dim3(16, B), 512, 0, stream>>>(xt, yt, lsr, yg, out);
}

// Round 15
// 37.330 us; speedup vs baseline: 1.2029x; 1.0481x over previous
//
#include <hip/hip_runtime.h>
#include <math.h>

#define G     1000
#define B     32
#define NC    2048
#define NT    2048
#define BN    (B * NT)
#define LOG2E 1.4426950408889634f
#define LN2PI 1.8378770664093453f   // ln(2*pi)

#if __has_builtin(__builtin_amdgcn_exp2f)
#define EXP2F(x) __builtin_amdgcn_exp2f(x)
#else
#define EXP2F(x) exp2f(x)
#endif

typedef float f32x2 __attribute__((ext_vector_type(2)));
#define PKFMA(a, b, c) __builtin_elementwise_fma(a, b, c)
#define SPLAT_LO(v)    __builtin_shufflevector(v, v, 0, 0)
#define SPLAT_HI(v)    __builtin_shufflevector(v, v, 1, 1)

// ---------------------------------------------------------------------------
// Kernel A v7: packed-f32 Gaussian recurrence along g. Pair consecutive g:
//   W2 = (W_2j, W_2j+1); step W2 *= S2, S2 = (q^2 r^{4j+1}, q^2 r^{4j+3});
//   S2 *= r^4. Per 2 g: pk_add + pk_fma + 2 pk_mul (half the scalar issue).
// Grid (16, B) = 512 blocks = 2/CU; block 512 = 8 n-slice waves x
// (8 g-runs x 8 n-subs); lane owns 8 g (4 pairs) + 32 strided n.
// ---------------------------------------------------------------------------
__global__ __launch_bounds__(512) void k_smooth(
    const float* __restrict__ xc, const float* __restrict__ yc,
    const float* __restrict__ ls_x, float* __restrict__ h,
    float* __restrict__ loss_slot) {
  __shared__ float2 sxy[NC];              // {s*x_n, y_n}, 16KB
  __shared__ float2 part[8][64];          // per-wave {h0,h1} partials, 4KB
  if (blockIdx.x == 0 && blockIdx.y == 0 && threadIdx.x == 0) *loss_slot = 0.f;

  int tid = threadIdx.x;
  int b = blockIdx.y, tile = blockIdx.x;
  float ls  = ls_x[0];
  float s   = sqrtf(0.5f * LOG2E) / ls;   // w = exp2(-(s*t - s*x)^2)
  float dlt = s * (4.4f / 999.f);

  const float* xb = xc + b * NC;
  const float* yb = yc + b * NC;
  for (int n = tid; n < NC; n += 512) sxy[n] = make_float2(s * xb[n], yb[n]);
  __syncthreads();

  int lane = tid & 63, w = tid >> 6;      // w = n-slice (256 n)
  int ns = lane & 7, gr = lane >> 3;      // 8 n-subs x 8 g-runs (8 g each)
  int g0 = tile * 64 + gr * 8;
  float v0 = s * -2.2f + dlt * (float)g0; // s*t at g0
  float r  = EXP2F(-2.f * dlt * dlt);
  float r3 = r * r * r;
  float r4 = r3 * r;
  const f32x2 R4 = {r4, r4};

  f32x2 h0p[4], h1p[4];
  #pragma unroll
  for (int j = 0; j < 4; ++j) { h0p[j] = (f32x2)0.f; h1p[j] = (f32x2)0.f; }

  const float2* base = sxy + w * 256 + ns;  // lane's n: +8 per step
  #pragma unroll 4
  for (int i = 0; i < 32; ++i) {
    float2 v = base[i * 8];
    float a  = v.x - v0;                  // u - v_g0
    float W0 = EXP2F(64.f - a * a);       // 2^64-scaled first weight
    float q  = EXP2F(fmaf(2.f * dlt, a, -dlt * dlt));
    float qq = q * q;
    f32x2 W2 = {W0, W0 * q};
    f32x2 S2 = {qq * r, qq * r3};
    f32x2 y2 = {v.y, v.y};
    #pragma unroll
    for (int j = 0; j < 4; ++j) {
      h0p[j] += W2;                       // v_pk_add_f32
      h1p[j] = PKFMA(W2, y2, h1p[j]);     // v_pk_fma_f32
      W2 *= S2;                           // v_pk_mul_f32
      S2 *= R4;                           // v_pk_mul_f32
    }
  }
  // reduce over the 8 n-subs (lane bits 0..2)
  #pragma unroll
  for (int m = 1; m < 8; m <<= 1) {
    #pragma unroll
    for (int j = 0; j < 4; ++j) {
      h0p[j].x += __shfl_xor(h0p[j].x, m);
      h0p[j].y += __shfl_xor(h0p[j].y, m);
      h1p[j].x += __shfl_xor(h1p[j].x, m);
      h1p[j].y += __shfl_xor(h1p[j].y, m);
    }
  }
  // static-index stores: lane ns==j stores pair j (rule #20: no runtime idx)
  #pragma unroll
  for (int j = 0; j < 4; ++j) {
    if (ns == j) {
      part[w][gr * 8 + 2 * j]     = make_float2(h0p[j].x, h1p[j].x);
      part[w][gr * 8 + 2 * j + 1] = make_float2(h0p[j].y, h1p[j].y);
    }
  }
  __syncthreads();

  if (tid < 64) {
    int g = tile * 64 + tid;
    if (g < G) {
      float d0 = 0.f, d1 = 0.f;
      #pragma unroll
      for (int k = 0; k < 8; ++k) { float2 pv = part[k][tid]; d0 += pv.x; d1 += pv.y; }
      d0 *= 0x1p-64f;
      d1 *= 0x1p-64f;
      h[(b * 2 + 0) * G + g] = d0;
      h[(b * 2 + 1) * G + g] = d1 / (d0 + 1e-8f);
    }
  }
}

// ---------------------------------------------------------------------------
// Kernel B v8 (frozen): full-occupancy mapping. L1/L3 POS=4 (256 thr),
// L2 POS=8 (256 thr). TILE=48, CSTR=68, grid (21 x B).
// ---------------------------------------------------------------------------
#define TILE  48
#define NTILE 21   // 21*48 = 1008 >= 1000
#define CSTR  68

template <int CIN, int COUT, int S4>
__device__ __forceinline__ void conv8(
    const float* __restrict__ in, float* __restrict__ out,
    const float4* __restrict__ wf4, const float* __restrict__ w4p,
    const float* __restrict__ bias, int tid) {
  if (tid < COUT * 8) {
    int oc = tid % COUT;
    int i0 = (tid / COUT) * 8;            // reads [i0,i0+12), writes [i0+2,i0+10)
    float acc[8];
    float bb = bias[oc];
    #pragma unroll
    for (int p = 0; p < 8; ++p) acc[p] = bb;
    for (int ic = 0; ic < CIN; ++ic) {
      const float4* ip = (const float4*)(in + ic * CSTR + i0);
      float4 A = ip[0], Bv = ip[1], C = ip[2];
      float v[12] = {A.x, A.y, A.z, A.w, Bv.x, Bv.y, Bv.z, Bv.w, C.x, C.y, C.z, C.w};
      float4 w = wf4[oc * S4 + ic];
      float w4v = w4p[ic * COUT + oc];
      #pragma unroll
      for (int p = 0; p < 8; ++p)
        acc[p] = fmaf(v[p], w.x, fmaf(v[p+1], w.y, fmaf(v[p+2], w.z,
                 fmaf(v[p+3], w.w, fmaf(v[p+4], w4v, acc[p])))));
    }
    float* op = out + oc * CSTR + i0 + 2;
    #pragma unroll
    for (int j = 0; j < 4; ++j)
      *(float2*)(op + 2 * j) = make_float2(fmaxf(acc[2*j], 0.f), fmaxf(acc[2*j+1], 0.f));
  }
}

template <int CIN, int COUT, int S4>
__device__ __forceinline__ void conv4(
    const float* __restrict__ in, float* __restrict__ out,
    const float4* __restrict__ wf4, const float* __restrict__ w4p,
    const float* __restrict__ bias, int tid) {
  int oc = tid % COUT;
  int i0 = (tid / COUT) * 4;              // 0..60
  float acc[4];
  float bb = bias[oc];
  #pragma unroll
  for (int p = 0; p < 4; ++p) acc[p] = bb;
  for (int ic = 0; ic < CIN; ++ic) {
    const float4* ip = (const float4*)(in + ic * CSTR + i0);
    float4 A = ip[0], Bv = ip[1];
    float v[8] = {A.x, A.y, A.z, A.w, Bv.x, Bv.y, Bv.z, Bv.w};
    float4 w = wf4[oc * S4 + ic];
    float w4v = w4p[ic * COUT + oc];
    #pragma unroll
    for (int p = 0; p < 4; ++p)
      acc[p] = fmaf(v[p], w.x, fmaf(v[p+1], w.y, fmaf(v[p+2], w.z,
               fmaf(v[p+3], w.w, fmaf(v[p+4], w4v, acc[p])))));
  }
  float* op = out + oc * CSTR + i0 + 2;
  *(float2*)op       = make_float2(fmaxf(acc[0], 0.f), fmaxf(acc[1], 0.f));
  *(float2*)(op + 2) = make_float2(fmaxf(acc[2], 0.f), fmaxf(acc[3], 0.f));
}

__global__ __launch_bounds__(256, 2) void k_conv(
    const float* __restrict__ h,
    const float* __restrict__ W1, const float* __restrict__ Bs1,
    const float* __restrict__ W2, const float* __restrict__ Bs2,
    const float* __restrict__ W3, const float* __restrict__ Bs3,
    const float* __restrict__ W4, const float* __restrict__ Bs4,
    float* __restrict__ yg) {
  __shared__ __align__(16) float bufA[32 * CSTR], bufB[32 * CSTR];
  __shared__ float4 wf1[16 * 3], wf2[32 * 17], wf3[16 * 33];
  __shared__ float  w41[2 * 16], w42[16 * 32], w43[32 * 16];
  __shared__ float  wt4[162];
  __shared__ float  sB1[16], sB2[32], sB3[16], sB4[2];

  int tid  = threadIdx.x;
  int tile = blockIdx.x, b = blockIdx.y;
  int ts   = tile * TILE;

  if (tid < 32) {                         // L1: oc<16, ic<2
    int oc = tid >> 1, ic = tid & 1, a = oc * 10 + ic * 5;
    wf1[oc * 3 + ic] = make_float4(W1[a], W1[a+1], W1[a+2], W1[a+3]);
    w41[ic * 16 + oc] = W1[a + 4];
  }
  for (int pr = tid; pr < 512; pr += 256) {   // L2: oc<32, ic<16
    int oc = pr >> 4, ic = pr & 15, a = oc * 80 + ic * 5;
    wf2[oc * 17 + ic] = make_float4(W2[a], W2[a+1], W2[a+2], W2[a+3]);
    w42[ic * 32 + oc] = W2[a + 4];
  }
  for (int pr = tid; pr < 512; pr += 256) {   // L3: oc<16, ic<32
    int oc = pr >> 5, ic = pr & 31, a = oc * 160 + ic * 5;
    wf3[oc * 33 + ic] = make_float4(W3[a], W3[a+1], W3[a+2], W3[a+3]);
    w43[ic * 16 + oc] = W3[a + 4];
  }
  for (int i = tid; i < 160; i += 256) wt4[(i / 80) * 81 + i % 80] = W4[i];
  if (tid < 16)       sB1[tid]      = Bs1[tid];
  else if (tid < 48)  sB2[tid - 16] = Bs2[tid - 16];
  else if (tid < 64)  sB3[tid - 48] = Bs3[tid - 48];
  else if (tid < 66)  sB4[tid - 64] = Bs4[tid - 64];

  for (int i = tid; i < 2 * CSTR; i += 256) {
    int c = i >= CSTR, col = i - c * CSTR;
    int g = ts + col - 10;
    bufA[c * CSTR + col] = (g >= 0 && g < G) ? h[(b * 2 + c) * G + g] : 0.f;
  }
  __syncthreads();

  conv4<2, 16, 3>(bufA, bufB, wf1, w41, sB1, tid);     // 256 thr
  __syncthreads();
  conv8<16, 32, 17>(bufB, bufA, wf2, w42, sB2, tid);   // 256 thr
  __syncthreads();
  conv4<32, 16, 33>(bufA, bufB, wf3, w43, sB3, tid);   // 256 thr
  __syncthreads();

  if (tid < 96) {
    int oc = tid >= 48;
    int j  = tid - oc * 48;
    int i  = 10 + j;
    float sacc = sB4[oc];
    #pragma unroll
    for (int ic = 0; ic < 16; ++ic) {
      const float* ip = bufB + ic * CSTR + i - 2;
      #pragma unroll
      for (int k = 0; k < 5; ++k)
        sacc = fmaf(ip[k], wt4[oc * 81 + ic * 5 + k], sacc);
    }
    int gp = ts + j;
    if (gp < G) {
      if (oc == 0) {
        yg[(b * 2 + 0) * G + gp] = sacc;
      } else {
        float sp_ = fmaxf(sacc, 0.f) + log1pf(__expf(-fabsf(sacc)));
        yg[(b * 2 + 1) * G + gp] = sp_;
      }
    }
  }
}

// ---------------------------------------------------------------------------
// Kernel C v7: packed-f32 Gaussian recurrence. acc pairs (mu,sg); state pairs
// (Wa,Wb), (qa,qb); splats via shufflevector (VOP3P opsel). Per f4 iter:
// 8 pk ops vs 16 scalar. Block 512 = 8 g-slices x 64 lanes; 2 t per lane.
// ---------------------------------------------------------------------------
__global__ __launch_bounds__(512) void k_pred(
    const float* __restrict__ xt, const float* __restrict__ yt,
    const float* __restrict__ ls_rho, const float* __restrict__ yg,
    float* __restrict__ out) {
  __shared__ float4 sp[512];              // {y0[2j], y1[2j], y0[2j+1], y1[2j+1]}
  __shared__ float pA0[512], pA1[512], pB0[512], pB1[512];
  __shared__ float red[8];

  int tid = threadIdx.x;
  int b = blockIdx.y, tile = blockIdx.x;
  float ls = ls_rho[0];
  float s  = sqrtf(0.5f * LOG2E) / ls;
  float dl = s * (4.4f / 999.f);

  const float* y0 = yg + (b * 2 + 0) * G;
  const float* y1 = yg + (b * 2 + 1) * G;
  {
    int g0 = 2 * tid, g1 = 2 * tid + 1;
    float a0 = (g0 < G) ? y0[g0] : 0.f, b0_ = (g0 < G) ? y1[g0] : 0.f;
    float a1 = (g1 < G) ? y0[g1] : 0.f, b1_ = (g1 < G) ? y1[g1] : 0.f;
    sp[tid] = make_float4(a0, b0_, a1, b1_);
  }
  __syncthreads();

  int lane = tid & 63, wv = tid >> 6;     // wv = g-slice 0..7 (128 g each)
  int ta = tile * 128 + lane;
  float ua = s * xt[b * NT + ta];
  float ub = s * xt[b * NT + ta + 64];
  float base = 2.2f * s - dl * (float)(wv * 128);
  float aa = ua + base, ab = ub + base;
  float r = EXP2F(-2.f * dl * dl);
  f32x2 Wab = {EXP2F(64.f - aa * aa), EXP2F(64.f - ab * ab)};
  f32x2 qab = {EXP2F(dl * (aa + aa) - dl * dl), EXP2F(dl * (ab + ab) - dl * dl)};
  const f32x2 R2 = {r, r};

  f32x2 accA = (f32x2)0.f, accB = (f32x2)0.f;   // (mu, sg)
  const float4* p = sp + wv * 64;
  #pragma unroll 4
  for (int i = 0; i < 64; ++i) {
    float4 v = p[i];
    f32x2 v01 = {v.x, v.y};
    f32x2 v23 = {v.z, v.w};
    accA = PKFMA(SPLAT_LO(Wab), v01, accA);
    accB = PKFMA(SPLAT_HI(Wab), v01, accB);
    Wab *= qab; qab *= R2;
    accA = PKFMA(SPLAT_LO(Wab), v23, accA);
    accB = PKFMA(SPLAT_HI(Wab), v23, accB);
    Wab *= qab; qab *= R2;
  }
  pA0[tid] = accA.x; pA1[tid] = accA.y; pB0[tid] = accB.x; pB1[tid] = accB.y;
  __syncthreads();

  float lp = 0.f;
  if (tid < 128) {
    int which = tid >> 6, l = tid & 63;
    int t = tile * 128 + which * 64 + l;
    const float* q0 = which ? pB0 : pA0;
    const float* q1 = which ? pB1 : pA1;
    float mu = 0.f, sg = 0.f;
    #pragma unroll
    for (int k = 0; k < 8; ++k) { mu += q0[l + 64 * k]; sg += q1[l + 64 * k]; }
    mu *= 0x1p-64f;
    sg *= 0x1p-64f;
    out[b * NT + t]      = mu;
    out[BN + b * NT + t] = sg;
    float z = (yt[b * NT + t] - mu) / sg;
    lp = -0.5f * z * z - __logf(sg) - 0.5f * LN2PI;
  }
  #pragma unroll
  for (int m = 32; m; m >>= 1) lp += __shfl_xor(lp, m);
  if ((tid & 63) == 0) red[tid >> 6] = lp;
  __syncthreads();
  if (tid == 0) {
    float tot = 0.f;
    #pragma unroll
    for (int i = 0; i < 8; ++i) tot += red[i];
    atomicAdd(out + 2 * BN, -tot * (1.f / (float)NT));
  }
}

extern "C" void kernel_launch(void* const* d_in, const int* in_sizes, int n_in,
                              void* d_out, int out_size, void* d_ws, size_t ws_size,
                              hipStream_t stream) {
  const float* xc  = (const float*)d_in[0];
  const float* yc  = (const float*)d_in[1];
  const float* xt  = (const float*)d_in[2];
  const float* yt  = (const float*)d_in[3];
  const float* lsx = (const float*)d_in[4];
  const float* lsr = (const float*)d_in[5];
  const float* W1  = (const float*)d_in[6];  const float* b1 = (const float*)d_in[7];
  const float* W2  = (const float*)d_in[8];  const float* b2 = (const float*)d_in[9];
  const float* W3  = (const float*)d_in[10]; const float* b3 = (const float*)d_in[11];
  const float* W4  = (const float*)d_in[12]; const float* b4 = (const float*)d_in[13];

  float* out = (float*)d_out;
  float* h   = (float*)d_ws;        // B*2*G
  float* yg  = h + B * 2 * G;       // B*2*G

  k_smooth<<<dim3(16, B), 512, 0, stream>>>(xc, yc, lsx, h, out + 2 * BN);
  k_conv<<<dim3(NTILE, B), 256, 0, stream>>>(h, W1, b1, W2, b2, W3, b3, W4, b4, yg);
  k_pred<<<dim3(16, B), 512, 0, stream>>>(xt, yt, lsr, yg, out);
}